// Round 1
// baseline (143.015 us; speedup 1.0000x reference)
//
#include <hip/hip_runtime.h>
#include <math.h>

#define N_Q   4096
#define N_DB  65536
#define DIM   32
#define KNN   5
#define NC    64                 // chunks
#define CH    (N_DB / NC)        // 1024 points per chunk
#define NSUB  32                 // 32-point subtiles per chunk
#define NCAND (NC * 6)           // 384 candidates per query
#define BIAS  256.0f

typedef _Float16 half8  __attribute__((ext_vector_type(8)));
typedef __fp16   fp16x2 __attribute__((ext_vector_type(2)));
typedef float floatx16  __attribute__((ext_vector_type(16)));

union H8  { half8 h; uint4 u4; unsigned u[4]; };
union F16 { floatx16 v; float4 q4[4]; unsigned w[16]; };
union HU  { fp16x2 h2; unsigned u; };

__device__ __forceinline__ unsigned cvt2(float a, float b) {
    HU t; t.h2 = __builtin_amdgcn_cvt_pkrtz(a, b);
    return t.u;
}

// ---------------- kernel 0: fp32 db -> tile-major fp16 image + biased norms ----------------
// DBh: [tile=p>>5][kgroup 0..3][row=p&31][8 halves]  (2 KB per 32-pt tile)
__global__ __launch_bounds__(256) void k_prep(const float* __restrict__ DB,
                                              uint4* __restrict__ DBh,
                                              float* __restrict__ hdb) {
    int p = blockIdx.x * 256 + threadIdx.x;
    const float4* src = (const float4*)(DB + (size_t)p * DIM);
    float4 f[8]; float s = 0.f;
#pragma unroll
    for (int j = 0; j < 8; ++j) {
        f[j] = src[j];
        s += f[j].x * f[j].x + f[j].y * f[j].y + f[j].z * f[j].z + f[j].w * f[j].w;
    }
    hdb[p] = BIAS - 0.5f * s;
    int t = p >> 5, r = p & 31;
#pragma unroll
    for (int gi = 0; gi < 4; ++gi) {
        uint4 g;
        g.x = cvt2(f[2 * gi].x, f[2 * gi].y);
        g.y = cvt2(f[2 * gi].z, f[2 * gi].w);
        g.z = cvt2(f[2 * gi + 1].x, f[2 * gi + 1].y);
        g.w = cvt2(f[2 * gi + 1].z, f[2 * gi + 1].w);
        DBh[(size_t)t * 128 + gi * 32 + r] = g;
    }
}

// ---------------- kernel 1: barrier-free MFMA scan + per-chunk approx top-6 ----------------
// 256 threads (4 waves) = 128-query tile x 1024-pt chunk; grid 32 x 64 = 2048 blocks.
// NO LDS, NO barriers: DBh is L2-resident (FETCH_SIZE==4.3MB total), so A-fragments are
// loaded straight from L2 into VGPRs with a 1-deep register ping-pong prefetch. Every
// wave is an independent stream -> latency hidden by occupancy, not by staging.
// launch_bounds(256,6): 85-reg cap; live set ~ a-slots(16)+b(8)+c0/p(16)+acc(16)+tk(6)+addr.
__global__ __launch_bounds__(256, 6) void k_scan(const float* __restrict__ Q,
                                                 const uint4* __restrict__ DBh,
                                                 const float* __restrict__ hdb,
                                                 unsigned* __restrict__ cand) {
    const int tid = threadIdx.x, lane = tid & 63, w = tid >> 6;   // w=0..3
    const int h = lane >> 5, qcol = lane & 31;
    const int chunk = blockIdx.x & (NC - 1);   // same-chunk blocks: stride 64 -> same XCD
    const int qb    = blockIdx.x >> 6;         // 0..31
    const int q     = qb * 128 + w * 32 + qcol;
    const int pbase = chunk * CH;

    // B-frags: convert this lane's query dims once
    const float* qp = Q + (size_t)q * DIM;
    float4 qa = *(const float4*)(qp + h * 8);
    float4 qb4 = *(const float4*)(qp + h * 8 + 4);
    float4 qc = *(const float4*)(qp + 16 + h * 8);
    float4 qd = *(const float4*)(qp + 16 + h * 8 + 4);
    H8 b1, b2;
    b1.u[0] = cvt2(qa.x, qa.y);   b1.u[1] = cvt2(qa.z, qa.w);
    b1.u[2] = cvt2(qb4.x, qb4.y); b1.u[3] = cvt2(qb4.z, qb4.w);
    b2.u[0] = cvt2(qc.x, qc.y);   b2.u[1] = cvt2(qc.z, qc.w);
    b2.u[2] = cvt2(qd.x, qd.y);   b2.u[3] = cvt2(qd.z, qd.w);

    // opaque VGPR mask -> pack is a single v_and_or_b32 (S2 = scalar id)
    unsigned maskv;
    asm("v_mov_b32 %0, 0xFFFFFC00" : "=v"(maskv));

    // per-lane A-frag base: tile (chunk*32+s), kgroup h (a1) / 2+h (a2), row lane&31
    const uint4* abase = DBh + (size_t)(pbase >> 5) * 128 + h * 32 + (lane & 31);
    const float* hb0   = hdb + pbase + 4 * h;     // c0 rows for this half

    float tk[6];
#pragma unroll
    for (int r = 0; r < 6; ++r) tk[r] = 0.f;

    constexpr int ROWC[16] = {0,1,2,3, 8,9,10,11, 16,17,18,19, 24,25,26,27}; // bit 2 free (=h)

    auto compute = [&](const H8& A1, const H8& A2, const int s) {
        const float* hbp = hb0 + s * 32;          // broadcast loads, L1/L2-hit
        F16 c0;
        c0.q4[0] = *(const float4*)(hbp + 0);
        c0.q4[1] = *(const float4*)(hbp + 8);
        c0.q4[2] = *(const float4*)(hbp + 16);
        c0.q4[3] = *(const float4*)(hbp + 24);
        floatx16 acc = __builtin_amdgcn_mfma_f32_32x32x16_f16(A1.h, b1.h, c0.v, 0, 0, 0);
        acc = __builtin_amdgcn_mfma_f32_32x32x16_f16(A2.h, b2.h, acc, 0, 0, 0);
        // pack 10-bit chunk-local id (subtile<<5 | rowc); h bit is OR-ed at chunk end
        F16 pk; pk.v = acc;
        const int meta = s << 5;                  // wave-uniform (scalar pipe)
        float p[16];
#pragma unroll
        for (int r = 0; r < 16; ++r)
            p[r] = __uint_as_float((pk.w[r] & maskv) | (unsigned)(meta | ROWC[r]));
        // true top-2 of 16 (max/min tournament; L-combines fold to v_max3)
        float hi[8], lo[8];
#pragma unroll
        for (int i = 0; i < 8; ++i) { hi[i] = fmaxf(p[2*i], p[2*i+1]); lo[i] = fminf(p[2*i], p[2*i+1]); }
        float H4[4], L4[4];
#pragma unroll
        for (int i = 0; i < 4; ++i) {
            H4[i] = fmaxf(hi[2*i], hi[2*i+1]);
            L4[i] = fmaxf(fmaxf(lo[2*i], lo[2*i+1]), fminf(hi[2*i], hi[2*i+1]));
        }
        float H2[2], L2[2];
#pragma unroll
        for (int i = 0; i < 2; ++i) {
            H2[i] = fmaxf(H4[2*i], H4[2*i+1]);
            L2[i] = fmaxf(fmaxf(L4[2*i], L4[2*i+1]), fminf(H4[2*i], H4[2*i+1]));
        }
        float c1 = fmaxf(H2[0], H2[1]);
        float c2 = fmaxf(fmaxf(L2[0], L2[1]), fminf(H2[0], H2[1]));
        // merge sorted pair (c1 >= c2) into sorted tk[6] via merge-path (15 ops, parallel)
        {
            float m01 = fminf(tk[0], c1), m02 = fminf(tk[1], c1);
            float m03 = fminf(tk[2], c1), m04 = fminf(tk[3], c1);
            float m05 = fminf(tk[4], c1);
            float m12 = fminf(tk[0], c2), m13 = fminf(tk[1], c2);
            float m14 = fminf(tk[2], c2), m15 = fminf(tk[3], c2);
            tk[0] = fmaxf(tk[0], c1);
            tk[1] = fmaxf(fmaxf(tk[1], m01), c2);
            tk[2] = fmaxf(fmaxf(tk[2], m02), m12);
            tk[3] = fmaxf(fmaxf(tk[3], m03), m13);
            tk[4] = fmaxf(fmaxf(tk[4], m04), m14);
            tk[5] = fmaxf(fmaxf(tk[5], m05), m15);
        }
    };

    // ping-pong register prefetch: load s+1 before computing s (depth-1; with >=5
    // independent waves/SIMD this buries the ~300cy L2 latency)
    H8 a1A, a2A, a1B, a2B;
    a1A.u4 = abase[0];
    a2A.u4 = abase[64];
    for (int s = 0; s < NSUB; s += 2) {
        a1B.u4 = abase[(size_t)(s + 1) * 128];
        a2B.u4 = abase[(size_t)(s + 1) * 128 + 64];
        compute(a1A, a2A, s);
        if (s + 2 < NSUB) {
            a1A.u4 = abase[(size_t)(s + 2) * 128];
            a2A.u4 = abase[(size_t)(s + 2) * 128 + 64];
        }
        compute(a1B, a2B, s + 1);
    }

    // set the h bit (bit 2 of id field) on the 6 survivors, once per chunk
#pragma unroll
    for (int r = 0; r < 6; ++r)
        tk[r] = __uint_as_float(__float_as_uint(tk[r]) | (unsigned)(h << 2));

    // cross-half merge: SNAPSHOT partner's list before mutating (R6 hazard fix)
    float other[6];
#pragma unroll
    for (int i = 0; i < 6; ++i) other[i] = __shfl_xor(tk[i], 32, 64);
#pragma unroll
    for (int i = 0; i < 6; ++i) {
        float val = other[i];
#pragma unroll
        for (int j = 0; j < 6; ++j) { float mx = fmaxf(tk[j], val); val = fminf(tk[j], val); tk[j] = mx; }
    }
    if (h == 0) {
        unsigned* dst = cand + ((size_t)q * NC + chunk) * 6;
#pragma unroll
        for (int r = 0; r < 6; ++r) dst[r] = __float_as_uint(tk[r]);
    }
}

// ---------------- kernel 2: global approx top-12, exact rescore, top-5, blend ----------------
__global__ __launch_bounds__(256) void k_merge(const float* __restrict__ Q,
                                               const float* __restrict__ DB,
                                               const float* __restrict__ AUX,
                                               const unsigned* __restrict__ cand,
                                               float* __restrict__ out) {
    const int tid = threadIdx.x, lane = tid & 63, w = tid >> 6;
    const int q = blockIdx.x * 4 + w;

    const unsigned* cq = cand + (size_t)q * NCAND + (size_t)lane * 6;
    float cur[6];
#pragma unroll
    for (int r = 0; r < 6; ++r) cur[r] = __uint_as_float(cq[r]);

    float wv[12]; int wl[12];
#pragma unroll
    for (int r = 0; r < 12; ++r) {
        float bv = cur[0]; int bl = lane;
#pragma unroll
        for (int off = 32; off >= 1; off >>= 1) {
            float ov = __shfl_xor(bv, off, 64);
            int   ol = __shfl_xor(bl, off, 64);
            if (ov > bv || (ov == bv && ol < bl)) { bv = ov; bl = ol; }
        }
        wv[r] = bv; wl[r] = bl;
        if (bl == lane) {
#pragma unroll
            for (int s = 0; s < 5; ++s) cur[s] = cur[s + 1];
            cur[5] = -1.f;
        }
    }

    float dist = 1e30f; int dbi = 0x7fffffff;
    if (lane < 12) {
        unsigned u = __float_as_uint(wv[lane]) & 1023u;   // chunk-local point id
        dbi = wl[lane] * CH + (int)u;
        const float4* dp = (const float4*)(DB + (size_t)dbi * DIM);
        const float4* qp = (const float4*)(Q + (size_t)q * DIM);
        float dot = 0.f, qs = 0.f, ds = 0.f;
#pragma unroll
        for (int j = 0; j < DIM / 4; ++j) {
            float4 a = qp[j], d = dp[j];
            dot += a.x * d.x + a.y * d.y + a.z * d.z + a.w * d.w;
            qs  += a.x * a.x + a.y * a.y + a.z * a.z + a.w * a.w;
            ds  += d.x * d.x + d.y * d.y + d.z * d.z + d.w * d.w;
        }
        dist = sqrtf(fmaxf(qs + ds - 2.f * dot, 0.f));
    }
    float wd[KNN]; int wi[KNN];
#pragma unroll
    for (int r = 0; r < KNN; ++r) {
        float bd = dist; int bi = dbi;
#pragma unroll
        for (int off = 32; off >= 1; off >>= 1) {
            float od = __shfl_xor(bd, off, 64);
            int   oi = __shfl_xor(bi, off, 64);
            if (od < bd || (od == bd && oi < bi)) { bd = od; bi = oi; }
        }
        wd[r] = bd; wi[r] = bi;
        if (dist == bd && dbi == bi) dist = 1e30f;
    }
    float ww[KNN], W = 0.f;
#pragma unroll
    for (int r = 0; r < KNN; ++r) { ww[r] = 1.f / (wd[r] + 1e-6f); W += ww[r]; }
    if (lane < DIM) {
        float o = 0.f;
#pragma unroll
        for (int r = 0; r < KNN; ++r) o += ww[r] * AUX[(size_t)wi[r] * DIM + lane];
        out[(size_t)q * DIM + lane] = o / W;
    }
}

// ---------------- launch ----------------
extern "C" void kernel_launch(void* const* d_in, const int* in_sizes, int n_in,
                              void* d_out, int out_size, void* d_ws, size_t ws_size,
                              hipStream_t stream) {
    const float* Q   = (const float*)d_in[0];
    const float* DB  = (const float*)d_in[1];
    const float* AUX = (const float*)d_in[2];
    float* out = (float*)d_out;

    char* ws = (char*)d_ws;
    uint4*    DBh = (uint4*)ws;                         ws += (size_t)(N_DB / 32) * 128 * 16; // 4 MB
    float*    hdb = (float*)ws;                         ws += (size_t)N_DB * 4;               // 256 KB
    unsigned* cand = (unsigned*)ws;                     // 4096*384*4 = 6 MB  (total 10.25 MB)

    k_prep<<<N_DB / 256, 256, 0, stream>>>(DB, DBh, hdb);
    k_scan<<<(N_Q / 128) * NC, 256, 0, stream>>>(Q, DBh, hdb, cand);
    k_merge<<<N_Q / 4, 256, 0, stream>>>(Q, DB, AUX, cand, out);
}

// Round 2
// 139.762 us; speedup vs baseline: 1.0233x; 1.0233x over previous
//
#include <hip/hip_runtime.h>
#include <math.h>

#define N_Q   4096
#define N_DB  65536
#define DIM   32
#define KNN   5
#define NC    64                 // chunks
#define CH    (N_DB / NC)        // 1024 points per chunk
#define NSUB  32                 // 32-point subtiles per chunk
#define NCAND (NC * 6)           // 384 candidates per query
#define BIAS  256.0f

typedef _Float16 half8  __attribute__((ext_vector_type(8)));
typedef __fp16   fp16x2 __attribute__((ext_vector_type(2)));
typedef float floatx16  __attribute__((ext_vector_type(16)));

union H8  { half8 h; uint4 u4; unsigned u[4]; };
union F16 { floatx16 v; float4 q4[4]; unsigned w[16]; };
union HU  { fp16x2 h2; unsigned u; };

__device__ __forceinline__ unsigned cvt2(float a, float b) {
    HU t; t.h2 = __builtin_amdgcn_cvt_pkrtz(a, b);
    return t.u;
}

// ---------------- kernel 0: fp32 db -> tile-major fp16 image + packed biased norm ----------------
// DBh: [tile=p>>5][kgroup 0..3][row=p&31][8 halves]  (2 KB per 32-pt tile)
// DBn: [p] one dword = fp16 pair (hi, lo), hi+lo ~= BIAS - 0.5*|db|^2  (split keeps err ~6e-5)
__global__ __launch_bounds__(256) void k_prep(const float* __restrict__ DB,
                                              uint4* __restrict__ DBh,
                                              unsigned* __restrict__ DBn) {
    int p = blockIdx.x * 256 + threadIdx.x;
    const float4* src = (const float4*)(DB + (size_t)p * DIM);
    float4 f[8]; float s = 0.f;
#pragma unroll
    for (int j = 0; j < 8; ++j) {
        f[j] = src[j];
        s += f[j].x * f[j].x + f[j].y * f[j].y + f[j].z * f[j].z + f[j].w * f[j].w;
    }
    float v  = BIAS - 0.5f * s;
    float hi = (float)(__fp16)v;      // fp16-representable head
    float lo = v - hi;                // exact residual (Sterbenz)
    DBn[p] = cvt2(hi, lo);            // k0 = hi (low half), k1 = lo
    int t = p >> 5, r = p & 31;
#pragma unroll
    for (int gi = 0; gi < 4; ++gi) {
        uint4 g;
        g.x = cvt2(f[2 * gi].x, f[2 * gi].y);
        g.y = cvt2(f[2 * gi].z, f[2 * gi].w);
        g.z = cvt2(f[2 * gi + 1].x, f[2 * gi + 1].y);
        g.w = cvt2(f[2 * gi + 1].z, f[2 * gi + 1].w);
        DBh[(size_t)t * 128 + gi * 32 + r] = g;
    }
}

// ---------------- kernel 1: barrier-free MFMA scan + per-chunk approx top-6 ----------------
// 256 threads (4 waves) = 128-query tile x 1024-pt chunk; grid 32 x 64 = 2048 blocks.
// NO LDS, NO barriers, NO c0 loads: the biased norm rides in a third K=16 MFMA
// (A3 = [hi,lo,0..], B3 = [1,1,0..]), so the only per-subtile memory traffic is
// 2x dwordx4 + 1x dword, all prefetched distance-2 (4 named slots, unroll-4 --
// static indexing, no scratch). (256,5): 102-reg cap, ~95 live -> 5 waves/SIMD.
__global__ __launch_bounds__(256, 5) void k_scan(const float* __restrict__ Q,
                                                 const uint4* __restrict__ DBh,
                                                 const unsigned* __restrict__ DBn,
                                                 unsigned* __restrict__ cand) {
    const int tid = threadIdx.x, lane = tid & 63, w = tid >> 6;   // w=0..3
    const int h = lane >> 5, row = lane & 31;
    const int chunk = blockIdx.x & (NC - 1);   // same-chunk blocks: stride 64 -> same XCD
    const int qb    = blockIdx.x >> 6;         // 0..31
    const int q     = qb * 128 + w * 32 + row;
    const int pbase = chunk * CH;

    // B-frags: convert this lane's query dims once
    const float* qp = Q + (size_t)q * DIM;
    float4 qa = *(const float4*)(qp + h * 8);
    float4 qb4 = *(const float4*)(qp + h * 8 + 4);
    float4 qc = *(const float4*)(qp + 16 + h * 8);
    float4 qd = *(const float4*)(qp + 16 + h * 8 + 4);
    H8 b1, b2, b3;
    b1.u[0] = cvt2(qa.x, qa.y);   b1.u[1] = cvt2(qa.z, qa.w);
    b1.u[2] = cvt2(qb4.x, qb4.y); b1.u[3] = cvt2(qb4.z, qb4.w);
    b2.u[0] = cvt2(qc.x, qc.y);   b2.u[1] = cvt2(qc.z, qc.w);
    b2.u[2] = cvt2(qd.x, qd.y);   b2.u[3] = cvt2(qd.z, qd.w);
    b3.u[0] = (h == 0) ? cvt2(1.f, 1.f) : 0u;   // k0,k1 = 1 for the norm MFMA
    b3.u[1] = 0u; b3.u[2] = 0u; b3.u[3] = 0u;
    const unsigned hmask = (h == 0) ? 0xFFFFFFFFu : 0u;

    // opaque VGPR mask -> pack is a single v_and_or_b32 (S2 = scalar id)
    unsigned maskv;
    asm("v_mov_b32 %0, 0xFFFFFC00" : "=v"(maskv));

    // per-lane A-frag base: tile (chunk*32+s), kgroup h (a1) / 2+h (a2), row lane&31
    const uint4*    abase = DBh + (size_t)(pbase >> 5) * 128 + h * 32 + row;
    const unsigned* nbase = DBn + pbase + row;

    floatx16 zc;                       // constant zero C (MFMA D!=C leaves it intact)
#pragma unroll
    for (int r = 0; r < 16; ++r) zc[r] = 0.f;

    float tk[6];
#pragma unroll
    for (int r = 0; r < 6; ++r) tk[r] = 0.f;

    constexpr int ROWC[16] = {0,1,2,3, 8,9,10,11, 16,17,18,19, 24,25,26,27}; // bit 2 free (=h)

    auto compute = [&](const H8& A1, const H8& A2, unsigned A3u, const int s) {
        H8 a3;
        a3.u[0] = A3u & hmask;         // only h=0 lanes carry (hi,lo); h=1 k-slots are 8..15
        a3.u[1] = 0u; a3.u[2] = 0u; a3.u[3] = 0u;
        floatx16 acc = __builtin_amdgcn_mfma_f32_32x32x16_f16(a3.h, b3.h, zc, 0, 0, 0);
        acc = __builtin_amdgcn_mfma_f32_32x32x16_f16(A1.h, b1.h, acc, 0, 0, 0);
        acc = __builtin_amdgcn_mfma_f32_32x32x16_f16(A2.h, b2.h, acc, 0, 0, 0);
        // pack 10-bit chunk-local id (subtile<<5 | rowc); h bit is OR-ed at chunk end
        F16 pk; pk.v = acc;
        const int meta = s << 5;                  // wave-uniform (scalar pipe)
        float p[16];
#pragma unroll
        for (int r = 0; r < 16; ++r)
            p[r] = __uint_as_float((pk.w[r] & maskv) | (unsigned)(meta | ROWC[r]));
        // true top-2 of 16 (max/min tournament; L-combines fold to v_max3)
        float hi8[8], lo8[8];
#pragma unroll
        for (int i = 0; i < 8; ++i) { hi8[i] = fmaxf(p[2*i], p[2*i+1]); lo8[i] = fminf(p[2*i], p[2*i+1]); }
        float H4[4], L4[4];
#pragma unroll
        for (int i = 0; i < 4; ++i) {
            H4[i] = fmaxf(hi8[2*i], hi8[2*i+1]);
            L4[i] = fmaxf(fmaxf(lo8[2*i], lo8[2*i+1]), fminf(hi8[2*i], hi8[2*i+1]));
        }
        float H2[2], L2[2];
#pragma unroll
        for (int i = 0; i < 2; ++i) {
            H2[i] = fmaxf(H4[2*i], H4[2*i+1]);
            L2[i] = fmaxf(fmaxf(L4[2*i], L4[2*i+1]), fminf(H4[2*i], H4[2*i+1]));
        }
        float c1 = fmaxf(H2[0], H2[1]);
        float c2 = fmaxf(fmaxf(L2[0], L2[1]), fminf(H2[0], H2[1]));
        // merge sorted pair (c1 >= c2) into sorted tk[6] via merge-path (15 ops, parallel)
        {
            float m01 = fminf(tk[0], c1), m02 = fminf(tk[1], c1);
            float m03 = fminf(tk[2], c1), m04 = fminf(tk[3], c1);
            float m05 = fminf(tk[4], c1);
            float m12 = fminf(tk[0], c2), m13 = fminf(tk[1], c2);
            float m14 = fminf(tk[2], c2), m15 = fminf(tk[3], c2);
            tk[0] = fmaxf(tk[0], c1);
            tk[1] = fmaxf(fmaxf(tk[1], m01), c2);
            tk[2] = fmaxf(fmaxf(tk[2], m02), m12);
            tk[3] = fmaxf(fmaxf(tk[3], m03), m13);
            tk[4] = fmaxf(fmaxf(tk[4], m04), m14);
            tk[5] = fmaxf(fmaxf(tk[5], m05), m15);
        }
    };

    auto LD = [&](H8& x1, H8& x2, unsigned& x3, const int s) {
        const uint4* ap = abase + (size_t)s * 128;
        x1.u4 = ap[0];
        x2.u4 = ap[64];
        x3 = nbase[s * 32];
    };

    // distance-2 prefetch over 4 named slots (tail loads run <=6KB past the chunk --
    // still inside the DBh/DBn/cand workspace, results never consumed)
    H8 sA1, sA2, sB1, sB2, sC1, sC2, sD1, sD2;
    unsigned nA, nB, nC, nD;
    LD(sA1, sA2, nA, 0);
    LD(sB1, sB2, nB, 1);
    for (int s = 0; s < NSUB; s += 4) {
        LD(sC1, sC2, nC, s + 2);  compute(sA1, sA2, nA, s);
        LD(sD1, sD2, nD, s + 3);  compute(sB1, sB2, nB, s + 1);
        LD(sA1, sA2, nA, s + 4);  compute(sC1, sC2, nC, s + 2);
        LD(sB1, sB2, nB, s + 5);  compute(sD1, sD2, nD, s + 3);
    }

    // set the h bit (bit 2 of id field) on the 6 survivors, once per chunk
#pragma unroll
    for (int r = 0; r < 6; ++r)
        tk[r] = __uint_as_float(__float_as_uint(tk[r]) | (unsigned)(h << 2));

    // cross-half merge: SNAPSHOT partner's list before mutating (R6 hazard fix)
    float other[6];
#pragma unroll
    for (int i = 0; i < 6; ++i) other[i] = __shfl_xor(tk[i], 32, 64);
#pragma unroll
    for (int i = 0; i < 6; ++i) {
        float val = other[i];
#pragma unroll
        for (int j = 0; j < 6; ++j) { float mx = fmaxf(tk[j], val); val = fminf(tk[j], val); tk[j] = mx; }
    }
    if (h == 0) {
        unsigned* dst = cand + ((size_t)q * NC + chunk) * 6;
#pragma unroll
        for (int r = 0; r < 6; ++r) dst[r] = __float_as_uint(tk[r]);
    }
}

// ---------------- kernel 2: global approx top-12, exact rescore, top-5, blend ----------------
__global__ __launch_bounds__(256) void k_merge(const float* __restrict__ Q,
                                               const float* __restrict__ DB,
                                               const float* __restrict__ AUX,
                                               const unsigned* __restrict__ cand,
                                               float* __restrict__ out) {
    const int tid = threadIdx.x, lane = tid & 63, w = tid >> 6;
    const int q = blockIdx.x * 4 + w;

    const unsigned* cq = cand + (size_t)q * NCAND + (size_t)lane * 6;
    float cur[6];
#pragma unroll
    for (int r = 0; r < 6; ++r) cur[r] = __uint_as_float(cq[r]);

    float wv[12]; int wl[12];
#pragma unroll
    for (int r = 0; r < 12; ++r) {
        float bv = cur[0]; int bl = lane;
#pragma unroll
        for (int off = 32; off >= 1; off >>= 1) {
            float ov = __shfl_xor(bv, off, 64);
            int   ol = __shfl_xor(bl, off, 64);
            if (ov > bv || (ov == bv && ol < bl)) { bv = ov; bl = ol; }
        }
        wv[r] = bv; wl[r] = bl;
        if (bl == lane) {
#pragma unroll
            for (int s = 0; s < 5; ++s) cur[s] = cur[s + 1];
            cur[5] = -1.f;
        }
    }

    float dist = 1e30f; int dbi = 0x7fffffff;
    if (lane < 12) {
        unsigned u = __float_as_uint(wv[lane]) & 1023u;   // chunk-local point id
        dbi = wl[lane] * CH + (int)u;
        const float4* dp = (const float4*)(DB + (size_t)dbi * DIM);
        const float4* qp = (const float4*)(Q + (size_t)q * DIM);
        float dot = 0.f, qs = 0.f, ds = 0.f;
#pragma unroll
        for (int j = 0; j < DIM / 4; ++j) {
            float4 a = qp[j], d = dp[j];
            dot += a.x * d.x + a.y * d.y + a.z * d.z + a.w * d.w;
            qs  += a.x * a.x + a.y * a.y + a.z * a.z + a.w * a.w;
            ds  += d.x * d.x + d.y * d.y + d.z * d.z + d.w * d.w;
        }
        dist = sqrtf(fmaxf(qs + ds - 2.f * dot, 0.f));
    }
    float wd[KNN]; int wi[KNN];
#pragma unroll
    for (int r = 0; r < KNN; ++r) {
        float bd = dist; int bi = dbi;
#pragma unroll
        for (int off = 32; off >= 1; off >>= 1) {
            float od = __shfl_xor(bd, off, 64);
            int   oi = __shfl_xor(bi, off, 64);
            if (od < bd || (od == bd && oi < bi)) { bd = od; bi = oi; }
        }
        wd[r] = bd; wi[r] = bi;
        if (dist == bd && dbi == bi) dist = 1e30f;
    }
    float ww[KNN], W = 0.f;
#pragma unroll
    for (int r = 0; r < KNN; ++r) { ww[r] = 1.f / (wd[r] + 1e-6f); W += ww[r]; }
    if (lane < DIM) {
        float o = 0.f;
#pragma unroll
        for (int r = 0; r < KNN; ++r) o += ww[r] * AUX[(size_t)wi[r] * DIM + lane];
        out[(size_t)q * DIM + lane] = o / W;
    }
}

// ---------------- launch ----------------
extern "C" void kernel_launch(void* const* d_in, const int* in_sizes, int n_in,
                              void* d_out, int out_size, void* d_ws, size_t ws_size,
                              hipStream_t stream) {
    const float* Q   = (const float*)d_in[0];
    const float* DB  = (const float*)d_in[1];
    const float* AUX = (const float*)d_in[2];
    float* out = (float*)d_out;

    char* ws = (char*)d_ws;
    uint4*    DBh = (uint4*)ws;                         ws += (size_t)(N_DB / 32) * 128 * 16; // 4 MB
    unsigned* DBn = (unsigned*)ws;                      ws += (size_t)N_DB * 4;               // 256 KB
    unsigned* cand = (unsigned*)ws;                     // 4096*384*4 = 6 MB  (total 10.25 MB)

    k_prep<<<N_DB / 256, 256, 0, stream>>>(DB, DBh, DBn);
    k_scan<<<(N_Q / 128) * NC, 256, 0, stream>>>(Q, DBh, DBn, cand);
    k_merge<<<N_Q / 4, 256, 0, stream>>>(Q, DB, AUX, cand, out);
}